// Round 1
// baseline (200.233 us; speedup 1.0000x reference)
//
#include <hip/hip_runtime.h>

// ---------------------------------------------------------------------------
// Shapes (all fp32):
//  x        (10,3,250,250)
//  conv1    5x5 stride2 pad1 -> h1 (10,6,124,124) relu
//  pool 2x2 stride1          -> p1 (10,6,123,123)
//  conv2    3x3 stride2 pad1 -> h2 (10,15,62,62) relu
//  pool 2x2 stride1          -> p2 (10,15,61,61)  == flat (10,55815)
//  fc1  (120,55815) relu -> out1 (10,120)
//  fc2  (84,120) relu, fc3 (1,84) -> h3 (10,)
//  s1 = tanh(qnn_w1(20,10) @ h3) ; fs = tanh(qnn_w2(5,20) @ s1)  (5,)
//  d2[n] = sum_i (fs[i]-ts[n,i])^2 ; K = exp(-d2)
//  out[c] = sum_n K[n]*kcls_w[c,n] + kcls_b[c]   -> (1,2)
// ---------------------------------------------------------------------------

__global__ void conv1_relu_k(const float* __restrict__ x, const float* __restrict__ w,
                             const float* __restrict__ bias, float* __restrict__ out) {
    int idx = blockIdx.x * blockDim.x + threadIdx.x;
    const int total = 10 * 6 * 124 * 124;
    if (idx >= total) return;
    int ox = idx % 124;
    int oy = (idx / 124) % 124;
    int oc = (idx / (124 * 124)) % 6;
    int b  = idx / (124 * 124 * 6);
    float acc = bias[oc];
    int iy0 = oy * 2 - 1, ix0 = ox * 2 - 1;
    for (int ic = 0; ic < 3; ++ic) {
        const float* xp = x + (size_t)(b * 3 + ic) * 250 * 250;
        const float* wp = w + (oc * 3 + ic) * 25;
        #pragma unroll
        for (int ky = 0; ky < 5; ++ky) {
            int iy = iy0 + ky;
            if ((unsigned)iy >= 250u) continue;
            #pragma unroll
            for (int kx = 0; kx < 5; ++kx) {
                int ix = ix0 + kx;
                if ((unsigned)ix >= 250u) continue;
                acc += wp[ky * 5 + kx] * xp[iy * 250 + ix];
            }
        }
    }
    out[idx] = fmaxf(acc, 0.f);
}

// 2x2 stride-1 VALID maxpool: in (BC, Hin, Hin) -> out (BC, Hin-1, Hin-1)
__global__ void maxpool_k(const float* __restrict__ in, float* __restrict__ out,
                          int Hin, int total) {
    int idx = blockIdx.x * blockDim.x + threadIdx.x;
    if (idx >= total) return;
    int Ho = Hin - 1;
    int xp = idx % Ho;
    int yp = (idx / Ho) % Ho;
    int rest = idx / (Ho * Ho);   // b*C + c
    const float* p = in + ((size_t)rest * Hin + yp) * Hin + xp;
    float m = fmaxf(fmaxf(p[0], p[1]), fmaxf(p[Hin], p[Hin + 1]));
    out[idx] = m;
}

__global__ void conv2_relu_k(const float* __restrict__ in, const float* __restrict__ w,
                             const float* __restrict__ bias, float* __restrict__ out) {
    int idx = blockIdx.x * blockDim.x + threadIdx.x;
    const int total = 10 * 15 * 62 * 62;
    if (idx >= total) return;
    int ox = idx % 62;
    int oy = (idx / 62) % 62;
    int oc = (idx / (62 * 62)) % 15;
    int b  = idx / (62 * 62 * 15);
    float acc = bias[oc];
    int iy0 = oy * 2 - 1, ix0 = ox * 2 - 1;
    for (int ic = 0; ic < 6; ++ic) {
        const float* ip = in + (size_t)(b * 6 + ic) * 123 * 123;
        const float* wp = w + (oc * 6 + ic) * 9;
        #pragma unroll
        for (int ky = 0; ky < 3; ++ky) {
            int iy = iy0 + ky;
            if ((unsigned)iy >= 123u) continue;
            #pragma unroll
            for (int kx = 0; kx < 3; ++kx) {
                int ix = ix0 + kx;
                if ((unsigned)ix >= 123u) continue;
                acc += wp[ky * 3 + kx] * ip[iy * 123 + ix];
            }
        }
    }
    out[idx] = fmaxf(acc, 0.f);
}

// fc1: one block per output row (120 blocks, 256 threads).
// Each thread keeps 10 batch accumulators; fc1_w is read exactly once.
__global__ void fc1_k(const float* __restrict__ act /*(10,55815)*/,
                      const float* __restrict__ w /*(120,55815)*/,
                      const float* __restrict__ bias,
                      float* __restrict__ out /*(10,120)*/) {
    const int K = 55815;
    int row = blockIdx.x;
    int tid = threadIdx.x;
    const float* wr = w + (size_t)row * K;
    float acc[10];
    #pragma unroll
    for (int b = 0; b < 10; ++b) acc[b] = 0.f;
    for (int k = tid; k < K; k += 256) {
        float wv = wr[k];
        #pragma unroll
        for (int b = 0; b < 10; ++b) acc[b] += wv * act[(size_t)b * K + k];
    }
    __shared__ float red[4 * 10];
    int wave = tid >> 6, lane = tid & 63;
    #pragma unroll
    for (int b = 0; b < 10; ++b) {
        float v = acc[b];
        for (int off = 32; off > 0; off >>= 1) v += __shfl_down(v, off);
        if (lane == 0) red[wave * 10 + b] = v;
    }
    __syncthreads();
    if (tid < 10) {
        float s = red[0 * 10 + tid] + red[1 * 10 + tid] + red[2 * 10 + tid] + red[3 * 10 + tid];
        out[tid * 120 + row] = fmaxf(s + bias[row], 0.f);
    }
}

// fc2 + fc3 + qnn head, single block (deterministic).
__global__ void head_k(const float* __restrict__ out1 /*(10,120)*/,
                       const float* __restrict__ fc2_w, const float* __restrict__ fc2_b,
                       const float* __restrict__ fc3_w, const float* __restrict__ fc3_b,
                       const float* __restrict__ qnn_w1, const float* __restrict__ qnn_w2,
                       float* __restrict__ fs_out /*(5,)*/) {
    __shared__ float s_in[1200];
    __shared__ float s_fc2[840];
    __shared__ float s_h3[10];
    __shared__ float s_s1[20];
    int tid = threadIdx.x;
    for (int i = tid; i < 1200; i += 256) s_in[i] = out1[i];
    __syncthreads();
    for (int p = tid; p < 840; p += 256) {
        int b = p / 84, j = p % 84;
        float acc = fc2_b[j];
        for (int k = 0; k < 120; ++k) acc += s_in[b * 120 + k] * fc2_w[j * 120 + k];
        s_fc2[b * 84 + j] = fmaxf(acc, 0.f);
    }
    __syncthreads();
    if (tid < 10) {
        float acc = fc3_b[0];
        for (int j = 0; j < 84; ++j) acc += s_fc2[tid * 84 + j] * fc3_w[j];
        s_h3[tid] = acc;
    }
    __syncthreads();
    if (tid < 20) {
        float acc = 0.f;
        for (int b = 0; b < 10; ++b) acc += qnn_w1[tid * 10 + b] * s_h3[b];
        s_s1[tid] = tanhf(acc);
    }
    __syncthreads();
    if (tid < 5) {
        float acc = 0.f;
        for (int j = 0; j < 20; ++j) acc += qnn_w2[tid * 20 + j] * s_s1[j];
        fs_out[tid] = tanhf(acc);
    }
}

// RBF kernel classifier, stage 1: 32 blocks x 256 threads, 1 sample/thread.
__global__ void cls_partial_k(const float* __restrict__ fs,
                              const float* __restrict__ ts /*(8192,5)*/,
                              const float* __restrict__ kw /*(2,8192)*/,
                              float* __restrict__ partials /*(32,2)*/) {
    int tid = threadIdx.x;
    int n = blockIdx.x * 256 + tid;
    float f0 = fs[0], f1 = fs[1], f2 = fs[2], f3 = fs[3], f4 = fs[4];
    const float* t = ts + (size_t)n * 5;
    float d0 = f0 - t[0], d1 = f1 - t[1], d2 = f2 - t[2], d3 = f3 - t[3], d4 = f4 - t[4];
    float dd = d0 * d0 + d1 * d1 + d2 * d2 + d3 * d3 + d4 * d4;
    float Kv = expf(-dd);
    float a0 = Kv * kw[n];
    float a1 = Kv * kw[8192 + n];
    for (int off = 32; off > 0; off >>= 1) {
        a0 += __shfl_down(a0, off);
        a1 += __shfl_down(a1, off);
    }
    __shared__ float l0[4], l1[4];
    int wave = tid >> 6, lane = tid & 63;
    if (lane == 0) { l0[wave] = a0; l1[wave] = a1; }
    __syncthreads();
    if (tid == 0) {
        partials[blockIdx.x * 2 + 0] = l0[0] + l0[1] + l0[2] + l0[3];
        partials[blockIdx.x * 2 + 1] = l1[0] + l1[1] + l1[2] + l1[3];
    }
}

__global__ void cls_final_k(const float* __restrict__ partials,
                            const float* __restrict__ kb, float* __restrict__ out) {
    int c = threadIdx.x;
    if (c < 2) {
        float acc = kb[c];
        for (int i = 0; i < 32; ++i) acc += partials[i * 2 + c];
        out[c] = acc;
    }
}

extern "C" void kernel_launch(void* const* d_in, const int* in_sizes, int n_in,
                              void* d_out, int out_size, void* d_ws, size_t ws_size,
                              hipStream_t stream) {
    const float* x        = (const float*)d_in[0];
    const float* conv1_w  = (const float*)d_in[1];
    const float* conv1_b  = (const float*)d_in[2];
    const float* conv2_w  = (const float*)d_in[3];
    const float* conv2_b  = (const float*)d_in[4];
    const float* fc1_w    = (const float*)d_in[5];
    const float* fc1_b    = (const float*)d_in[6];
    const float* fc2_w    = (const float*)d_in[7];
    const float* fc2_b    = (const float*)d_in[8];
    const float* fc3_w    = (const float*)d_in[9];
    const float* fc3_b    = (const float*)d_in[10];
    const float* qnn_w1   = (const float*)d_in[11];
    const float* qnn_w2   = (const float*)d_in[12];
    const float* tstates  = (const float*)d_in[13];
    const float* kcls_w   = (const float*)d_in[14];
    const float* kcls_b   = (const float*)d_in[15];

    float* ws = (float*)d_ws;
    float* h1       = ws;                 // 922560
    float* p1       = h1 + 922560;        // 907740
    float* h2       = p1 + 907740;        // 576600
    float* p2       = h2 + 576600;        // 558150
    float* out1     = p2 + 558150;        // 1200
    float* fs       = out1 + 1200;        // 8
    float* partials = fs + 8;             // 64

    const int n_conv1 = 10 * 6 * 124 * 124;     // 922560
    const int n_pool1 = 10 * 6 * 123 * 123;     // 907740
    const int n_conv2 = 10 * 15 * 62 * 62;      // 576600
    const int n_pool2 = 10 * 15 * 61 * 61;      // 558150

    conv1_relu_k<<<(n_conv1 + 255) / 256, 256, 0, stream>>>(x, conv1_w, conv1_b, h1);
    maxpool_k<<<(n_pool1 + 255) / 256, 256, 0, stream>>>(h1, p1, 124, n_pool1);
    conv2_relu_k<<<(n_conv2 + 255) / 256, 256, 0, stream>>>(p1, conv2_w, conv2_b, h2);
    maxpool_k<<<(n_pool2 + 255) / 256, 256, 0, stream>>>(h2, p2, 62, n_pool2);
    fc1_k<<<120, 256, 0, stream>>>(p2, fc1_w, fc1_b, out1);
    head_k<<<1, 256, 0, stream>>>(out1, fc2_w, fc2_b, fc3_w, fc3_b, qnn_w1, qnn_w2, fs);
    cls_partial_k<<<32, 256, 0, stream>>>(fs, tstates, kcls_w, partials);
    cls_final_k<<<1, 64, 0, stream>>>(partials, kcls_b, (float*)d_out);
}

// Round 2
// 123.587 us; speedup vs baseline: 1.6202x; 1.6202x over previous
//
#include <hip/hip_runtime.h>

// ---------------------------------------------------------------------------
//  x        (10,3,250,250)
//  conv1    5x5 stride2 pad1 -> h1 (10,6,124,124) relu
//  pool 2x2 stride1          -> p1 (10,6,123,123)
//  conv2    3x3 stride2 pad1 -> h2 (10,15,62,62) relu
//  pool 2x2 stride1          -> p2 (10,15,61,61)  == flat (10,55815)
//  fc1  (120,55815) relu -> out1 (10,120)   [split-K: 15 rowtiles x 37 chunks]
//  fc2  (84,120) relu, fc3 (1,84) -> h3 (10,)
//  s1 = tanh(qnn_w1(20,10) @ h3) ; fs = tanh(qnn_w2(5,20) @ s1)  (5,)
//  d2[n] = sum_i (fs[i]-ts[n,i])^2 ; K = exp(-d2)
//  out[c] = sum_n K[n]*kcls_w[c,n] + kcls_b[c]   -> (1,2)
// ---------------------------------------------------------------------------

__global__ void conv1_relu_k(const float* __restrict__ x, const float* __restrict__ w,
                             const float* __restrict__ bias, float* __restrict__ out) {
    int idx = blockIdx.x * blockDim.x + threadIdx.x;
    const int total = 10 * 6 * 124 * 124;
    if (idx >= total) return;
    int ox = idx % 124;
    int oy = (idx / 124) % 124;
    int oc = (idx / (124 * 124)) % 6;
    int b  = idx / (124 * 124 * 6);
    float acc = bias[oc];
    int iy0 = oy * 2 - 1, ix0 = ox * 2 - 1;
    for (int ic = 0; ic < 3; ++ic) {
        const float* xp = x + (size_t)(b * 3 + ic) * 250 * 250;
        const float* wp = w + (oc * 3 + ic) * 25;
        #pragma unroll
        for (int ky = 0; ky < 5; ++ky) {
            int iy = iy0 + ky;
            if ((unsigned)iy >= 250u) continue;
            #pragma unroll
            for (int kx = 0; kx < 5; ++kx) {
                int ix = ix0 + kx;
                if ((unsigned)ix >= 250u) continue;
                acc += wp[ky * 5 + kx] * xp[iy * 250 + ix];
            }
        }
    }
    out[idx] = fmaxf(acc, 0.f);
}

// 2x2 stride-1 VALID maxpool: in (BC, Hin, Hin) -> out (BC, Hin-1, Hin-1)
__global__ void maxpool_k(const float* __restrict__ in, float* __restrict__ out,
                          int Hin, int total) {
    int idx = blockIdx.x * blockDim.x + threadIdx.x;
    if (idx >= total) return;
    int Ho = Hin - 1;
    int xp = idx % Ho;
    int yp = (idx / Ho) % Ho;
    int rest = idx / (Ho * Ho);   // b*C + c
    const float* p = in + ((size_t)rest * Hin + yp) * Hin + xp;
    float m = fmaxf(fmaxf(p[0], p[1]), fmaxf(p[Hin], p[Hin + 1]));
    out[idx] = m;
}

__global__ void conv2_relu_k(const float* __restrict__ in, const float* __restrict__ w,
                             const float* __restrict__ bias, float* __restrict__ out) {
    int idx = blockIdx.x * blockDim.x + threadIdx.x;
    const int total = 10 * 15 * 62 * 62;
    if (idx >= total) return;
    int ox = idx % 62;
    int oy = (idx / 62) % 62;
    int oc = (idx / (62 * 62)) % 15;
    int b  = idx / (62 * 62 * 15);
    float acc = bias[oc];
    int iy0 = oy * 2 - 1, ix0 = ox * 2 - 1;
    for (int ic = 0; ic < 6; ++ic) {
        const float* ip = in + (size_t)(b * 6 + ic) * 123 * 123;
        const float* wp = w + (oc * 6 + ic) * 9;
        #pragma unroll
        for (int ky = 0; ky < 3; ++ky) {
            int iy = iy0 + ky;
            if ((unsigned)iy >= 123u) continue;
            #pragma unroll
            for (int kx = 0; kx < 3; ++kx) {
                int ix = ix0 + kx;
                if ((unsigned)ix >= 123u) continue;
                acc += wp[ky * 3 + kx] * ip[iy * 123 + ix];
            }
        }
    }
    out[idx] = fmaxf(acc, 0.f);
}

// ---------------- fc1: split-K, two stage ----------------
#define FC1_K      55815
#define FC1_CHUNK  1536
#define FC1_NC     37        // ceil(55815/1536)
#define FC1_RT     15        // row tiles of 8

// grid (15, 37), block 256. Wave w (0..3) owns rows rt*8 + {2w, 2w+1}.
// All 4 waves share the same k range -> act lines hit L1.
__global__ void fc1_partial_k(const float* __restrict__ act /*(10,K)*/,
                              const float* __restrict__ w   /*(120,K)*/,
                              float* __restrict__ partials  /*(15,37,8,10)*/) {
    int rt  = blockIdx.x;
    int c   = blockIdx.y;
    int tid = threadIdx.x;
    int wave = tid >> 6, lane = tid & 63;
    int k0 = c * FC1_CHUNK;
    int k1 = k0 + FC1_CHUNK; if (k1 > FC1_K) k1 = FC1_K;
    int r0 = rt * 8 + wave * 2;           // two rows per wave
    const float* w0 = w + (size_t)r0 * FC1_K;
    const float* w1 = w + (size_t)(r0 + 1) * FC1_K;

    float acc0[10], acc1[10];
    #pragma unroll
    for (int b = 0; b < 10; ++b) { acc0[b] = 0.f; acc1[b] = 0.f; }

    for (int k = k0 + lane; k < k1; k += 64) {
        float a[10];
        #pragma unroll
        for (int b = 0; b < 10; ++b) a[b] = act[(size_t)b * FC1_K + k];
        float wv0 = w0[k];
        float wv1 = w1[k];
        #pragma unroll
        for (int b = 0; b < 10; ++b) {
            acc0[b] += wv0 * a[b];
            acc1[b] += wv1 * a[b];
        }
    }
    #pragma unroll
    for (int b = 0; b < 10; ++b) {
        float v0 = acc0[b], v1 = acc1[b];
        for (int off = 32; off > 0; off >>= 1) {
            v0 += __shfl_down(v0, off);
            v1 += __shfl_down(v1, off);
        }
        if (lane == 0) {
            size_t base = (((size_t)rt * FC1_NC + c) * 8 + wave * 2) * 10;
            partials[base + b]      = v0;
            partials[base + 10 + b] = v1;
        }
    }
}

// 1200 outputs: (row, b). Sum 37 chunk partials, + bias, relu.
__global__ void fc1_reduce_k(const float* __restrict__ partials,
                             const float* __restrict__ bias,
                             float* __restrict__ out /*(10,120)*/) {
    int idx = blockIdx.x * blockDim.x + threadIdx.x;
    if (idx >= 1200) return;
    int b   = idx % 10;
    int row = idx / 10;
    int rt = row >> 3, r = row & 7;
    float s = 0.f;
    const float* p = partials + (((size_t)rt * FC1_NC) * 8 + r) * 10 + b;
    for (int c = 0; c < FC1_NC; ++c) s += p[(size_t)c * 80];
    out[b * 120 + row] = fmaxf(s + bias[row], 0.f);
}

// fc2 + fc3 + qnn head, single block (deterministic).
__global__ void head_k(const float* __restrict__ out1 /*(10,120)*/,
                       const float* __restrict__ fc2_w, const float* __restrict__ fc2_b,
                       const float* __restrict__ fc3_w, const float* __restrict__ fc3_b,
                       const float* __restrict__ qnn_w1, const float* __restrict__ qnn_w2,
                       float* __restrict__ fs_out /*(5,)*/) {
    __shared__ float s_in[1200];
    __shared__ float s_fc2[840];
    __shared__ float s_h3[10];
    __shared__ float s_s1[20];
    int tid = threadIdx.x;
    for (int i = tid; i < 1200; i += 256) s_in[i] = out1[i];
    __syncthreads();
    for (int p = tid; p < 840; p += 256) {
        int b = p / 84, j = p % 84;
        float acc = fc2_b[j];
        for (int k = 0; k < 120; ++k) acc += s_in[b * 120 + k] * fc2_w[j * 120 + k];
        s_fc2[b * 84 + j] = fmaxf(acc, 0.f);
    }
    __syncthreads();
    if (tid < 10) {
        float acc = fc3_b[0];
        for (int j = 0; j < 84; ++j) acc += s_fc2[tid * 84 + j] * fc3_w[j];
        s_h3[tid] = acc;
    }
    __syncthreads();
    if (tid < 20) {
        float acc = 0.f;
        for (int b = 0; b < 10; ++b) acc += qnn_w1[tid * 10 + b] * s_h3[b];
        s_s1[tid] = tanhf(acc);
    }
    __syncthreads();
    if (tid < 5) {
        float acc = 0.f;
        for (int j = 0; j < 20; ++j) acc += qnn_w2[tid * 20 + j] * s_s1[j];
        fs_out[tid] = tanhf(acc);
    }
}

// RBF kernel classifier, stage 1: 32 blocks x 256 threads, 1 sample/thread.
__global__ void cls_partial_k(const float* __restrict__ fs,
                              const float* __restrict__ ts /*(8192,5)*/,
                              const float* __restrict__ kw /*(2,8192)*/,
                              float* __restrict__ partials /*(32,2)*/) {
    int tid = threadIdx.x;
    int n = blockIdx.x * 256 + tid;
    float f0 = fs[0], f1 = fs[1], f2 = fs[2], f3 = fs[3], f4 = fs[4];
    const float* t = ts + (size_t)n * 5;
    float d0 = f0 - t[0], d1 = f1 - t[1], d2 = f2 - t[2], d3 = f3 - t[3], d4 = f4 - t[4];
    float dd = d0 * d0 + d1 * d1 + d2 * d2 + d3 * d3 + d4 * d4;
    float Kv = expf(-dd);
    float a0 = Kv * kw[n];
    float a1 = Kv * kw[8192 + n];
    for (int off = 32; off > 0; off >>= 1) {
        a0 += __shfl_down(a0, off);
        a1 += __shfl_down(a1, off);
    }
    __shared__ float l0[4], l1[4];
    int wave = tid >> 6, lane = tid & 63;
    if (lane == 0) { l0[wave] = a0; l1[wave] = a1; }
    __syncthreads();
    if (tid == 0) {
        partials[blockIdx.x * 2 + 0] = l0[0] + l0[1] + l0[2] + l0[3];
        partials[blockIdx.x * 2 + 1] = l1[0] + l1[1] + l1[2] + l1[3];
    }
}

__global__ void cls_final_k(const float* __restrict__ partials,
                            const float* __restrict__ kb, float* __restrict__ out) {
    int c = threadIdx.x;
    if (c < 2) {
        float acc = kb[c];
        for (int i = 0; i < 32; ++i) acc += partials[i * 2 + c];
        out[c] = acc;
    }
}

extern "C" void kernel_launch(void* const* d_in, const int* in_sizes, int n_in,
                              void* d_out, int out_size, void* d_ws, size_t ws_size,
                              hipStream_t stream) {
    const float* x        = (const float*)d_in[0];
    const float* conv1_w  = (const float*)d_in[1];
    const float* conv1_b  = (const float*)d_in[2];
    const float* conv2_w  = (const float*)d_in[3];
    const float* conv2_b  = (const float*)d_in[4];
    const float* fc1_w    = (const float*)d_in[5];
    const float* fc1_b    = (const float*)d_in[6];
    const float* fc2_w    = (const float*)d_in[7];
    const float* fc2_b    = (const float*)d_in[8];
    const float* fc3_w    = (const float*)d_in[9];
    const float* fc3_b    = (const float*)d_in[10];
    const float* qnn_w1   = (const float*)d_in[11];
    const float* qnn_w2   = (const float*)d_in[12];
    const float* tstates  = (const float*)d_in[13];
    const float* kcls_w   = (const float*)d_in[14];
    const float* kcls_b   = (const float*)d_in[15];

    float* ws = (float*)d_ws;
    float* h1        = ws;                  // 922560
    float* p1        = h1 + 922560;         // 907740
    float* h2        = p1 + 907740;         // 576600
    float* p2        = h2 + 576600;         // 558150
    float* out1      = p2 + 558150;         // 1200
    float* fs        = out1 + 1200;         // 8
    float* partials  = fs + 8;              // 64
    float* fc1_part  = partials + 64;       // 15*37*80 = 44400

    const int n_conv1 = 10 * 6 * 124 * 124;     // 922560
    const int n_pool1 = 10 * 6 * 123 * 123;     // 907740
    const int n_conv2 = 10 * 15 * 62 * 62;      // 576600
    const int n_pool2 = 10 * 15 * 61 * 61;      // 558150

    conv1_relu_k<<<(n_conv1 + 255) / 256, 256, 0, stream>>>(x, conv1_w, conv1_b, h1);
    maxpool_k<<<(n_pool1 + 255) / 256, 256, 0, stream>>>(h1, p1, 124, n_pool1);
    conv2_relu_k<<<(n_conv2 + 255) / 256, 256, 0, stream>>>(p1, conv2_w, conv2_b, h2);
    maxpool_k<<<(n_pool2 + 255) / 256, 256, 0, stream>>>(h2, p2, 62, n_pool2);
    fc1_partial_k<<<dim3(FC1_RT, FC1_NC), 256, 0, stream>>>(p2, fc1_w, fc1_part);
    fc1_reduce_k<<<5, 256, 0, stream>>>(fc1_part, fc1_b, out1);
    head_k<<<1, 256, 0, stream>>>(out1, fc2_w, fc2_b, fc3_w, fc3_b, qnn_w1, qnn_w2, fs);
    cls_partial_k<<<32, 256, 0, stream>>>(fs, tstates, kcls_w, partials);
    cls_final_k<<<1, 64, 0, stream>>>(partials, kcls_b, (float*)d_out);
}

// Round 3
// 96.405 us; speedup vs baseline: 2.0770x; 1.2820x over previous
//
#include <hip/hip_runtime.h>

// ---------------------------------------------------------------------------
//  x (10,3,250,250)
//  conv1 5x5 s2 p1 + relu -> (10,6,124,124); pool 2x2 s1 -> p1 (10,6,123,123)
//  conv2 3x3 s2 p1 + relu -> (10,15,62,62);  pool 2x2 s1 -> p2 (10,15,61,61)
//  fc1 (120,55815) relu -> (10,120)  [split-K partials, reduced in tail]
//  fc2 (84,120) relu, fc3 (1,84), qnn tanh x2 -> fs (5,)
//  RBF vs train_states (8192,5) -> K -> out (1,2)
// ---------------------------------------------------------------------------

// ================= conv1 + relu + maxpool fused =================
// grid (10, 62), block 256. Tile: 2 pool rows -> 3 conv rows -> 9 input rows.
__global__ __launch_bounds__(256) void convpool1_k(
    const float* __restrict__ x, const float* __restrict__ w,
    const float* __restrict__ bias, float* __restrict__ out /*(10,6,123,123)*/) {
    int b   = blockIdx.x;
    int py0 = blockIdx.y * 2;
    int n_py = (123 - py0) < 2 ? (123 - py0) : 2;
    int n_oy = n_py + 1;            // conv rows needed (pool window 2, stride 1)
    int iy0  = 2 * py0 - 1;
    int n_iy = 2 * n_oy + 3;        // input rows needed (5-tap, stride 2)

    __shared__ float sx[3][9][252]; // input tile, col = ix+1 (pad left)
    __shared__ float so[6][3][124]; // conv outputs

    int tid = threadIdx.x;

    // ---- stage input tile (coalesced, zero-padded) ----
    int total_x = 3 * n_iy * 252;
    for (int i = tid; i < total_x; i += 256) {
        int col = i % 252;
        int r   = (i / 252) % n_iy;
        int ic  = i / (252 * n_iy);
        int ix = col - 1, iy = iy0 + r;
        float v = 0.f;
        if ((unsigned)ix < 250u && (unsigned)iy < 250u)
            v = x[((size_t)(b * 3 + ic) * 250 + iy) * 250 + ix];
        sx[ic][r][col] = v;
    }
    __syncthreads();

    // ---- conv: each thread owns one (oyl, ox) for ALL 6 oc ----
    int total_pos = n_oy * 124;
    for (int p = tid; p < total_pos; p += 256) {
        int ox  = p % 124;
        int oyl = p / 124;
        float acc[6];
        #pragma unroll
        for (int o = 0; o < 6; ++o) acc[o] = bias[o];
        #pragma unroll
        for (int ic = 0; ic < 3; ++ic) {
            #pragma unroll
            for (int ky = 0; ky < 5; ++ky) {
                const float* xr = &sx[ic][2 * oyl + ky][2 * ox];
                #pragma unroll
                for (int kx = 0; kx < 5; ++kx) {
                    float xv = xr[kx];  // col = 2*ox+kx  (= ix+1)
                    #pragma unroll
                    for (int o = 0; o < 6; ++o)
                        acc[o] += w[((o * 3 + ic) * 5 + ky) * 5 + kx] * xv;
                }
            }
        }
        #pragma unroll
        for (int o = 0; o < 6; ++o) so[o][oyl][ox] = fmaxf(acc[o], 0.f);
    }
    __syncthreads();

    // ---- pool 2x2 s1 + store ----
    int total_p = 6 * n_py * 123;
    for (int i = tid; i < total_p; i += 256) {
        int px  = i % 123;
        int pyl = (i / 123) % n_py;
        int oc  = i / (123 * n_py);
        float v = fmaxf(fmaxf(so[oc][pyl][px],     so[oc][pyl][px + 1]),
                        fmaxf(so[oc][pyl + 1][px], so[oc][pyl + 1][px + 1]));
        out[((size_t)(b * 6 + oc) * 123 + (py0 + pyl)) * 123 + px] = v;
    }
}

// ================= conv2 + relu + maxpool fused =================
// grid (10, 31), block 192. Tile: 2 pool rows -> 3 conv rows -> 7 input rows.
__global__ __launch_bounds__(192) void convpool2_k(
    const float* __restrict__ in /*(10,6,123,123)*/, const float* __restrict__ w,
    const float* __restrict__ bias, float* __restrict__ out /*(10,15,61,61)*/) {
    int b   = blockIdx.x;
    int py0 = blockIdx.y * 2;
    int n_py = (61 - py0) < 2 ? (61 - py0) : 2;
    int n_oy = n_py + 1;
    int iy0  = 2 * py0 - 1;
    int n_iy = 2 * n_oy + 1;        // 3-tap, stride 2

    __shared__ float sx[6][7][126]; // col = ix+1
    __shared__ float so[15][3][62];

    int tid = threadIdx.x;

    int total_x = 6 * n_iy * 126;
    for (int i = tid; i < total_x; i += 192) {
        int col = i % 126;
        int r   = (i / 126) % n_iy;
        int ic  = i / (126 * n_iy);
        int ix = col - 1, iy = iy0 + r;
        float v = 0.f;
        if ((unsigned)ix < 123u && (unsigned)iy < 123u)
            v = in[((size_t)(b * 6 + ic) * 123 + iy) * 123 + ix];
        sx[ic][r][col] = v;
    }
    __syncthreads();

    int total_pos = n_oy * 62;
    for (int p = tid; p < total_pos; p += 192) {
        int ox  = p % 62;
        int oyl = p / 62;
        float acc[15];
        #pragma unroll
        for (int o = 0; o < 15; ++o) acc[o] = bias[o];
        #pragma unroll
        for (int ic = 0; ic < 6; ++ic) {
            #pragma unroll
            for (int ky = 0; ky < 3; ++ky) {
                const float* xr = &sx[ic][2 * oyl + ky][2 * ox];
                #pragma unroll
                for (int kx = 0; kx < 3; ++kx) {
                    float xv = xr[kx];
                    #pragma unroll
                    for (int o = 0; o < 15; ++o)
                        acc[o] += w[((o * 6 + ic) * 3 + ky) * 3 + kx] * xv;
                }
            }
        }
        #pragma unroll
        for (int o = 0; o < 15; ++o) so[o][oyl][ox] = fmaxf(acc[o], 0.f);
    }
    __syncthreads();

    int total_p = 15 * n_py * 61;
    for (int i = tid; i < total_p; i += 192) {
        int px  = i % 61;
        int pyl = (i / 61) % n_py;
        int oc  = i / (61 * n_py);
        float v = fmaxf(fmaxf(so[oc][pyl][px],     so[oc][pyl][px + 1]),
                        fmaxf(so[oc][pyl + 1][px], so[oc][pyl + 1][px + 1]));
        out[((size_t)(b * 15 + oc) * 61 + (py0 + pyl)) * 61 + px] = v;
    }
}

// ================= fc1: split-K partials =================
#define FC1_K      55815
#define FC1_CHUNK  1536
#define FC1_NC     37
#define FC1_RT     15

// grid (15, 37), block 256. Wave w owns rows rt*8 + {2w, 2w+1}.
__global__ __launch_bounds__(256) void fc1_partial_k(
    const float* __restrict__ act /*(10,K)*/,
    const float* __restrict__ w   /*(120,K)*/,
    float* __restrict__ partials  /*(15,37,8,10)*/) {
    int rt  = blockIdx.x;
    int c   = blockIdx.y;
    int tid = threadIdx.x;
    int wave = tid >> 6, lane = tid & 63;
    int k0 = c * FC1_CHUNK;
    int k1 = k0 + FC1_CHUNK; if (k1 > FC1_K) k1 = FC1_K;
    int r0 = rt * 8 + wave * 2;
    const float* w0 = w + (size_t)r0 * FC1_K;
    const float* w1 = w + (size_t)(r0 + 1) * FC1_K;

    float acc0[10], acc1[10];
    #pragma unroll
    for (int b = 0; b < 10; ++b) { acc0[b] = 0.f; acc1[b] = 0.f; }

    for (int k = k0 + lane; k < k1; k += 64) {
        float a[10];
        #pragma unroll
        for (int b = 0; b < 10; ++b) a[b] = act[(size_t)b * FC1_K + k];
        float wv0 = w0[k];
        float wv1 = w1[k];
        #pragma unroll
        for (int b = 0; b < 10; ++b) {
            acc0[b] += wv0 * a[b];
            acc1[b] += wv1 * a[b];
        }
    }
    #pragma unroll
    for (int b = 0; b < 10; ++b) {
        float v0 = acc0[b], v1 = acc1[b];
        for (int off = 32; off > 0; off >>= 1) {
            v0 += __shfl_down(v0, off);
            v1 += __shfl_down(v1, off);
        }
        if (lane == 0) {
            size_t base = (((size_t)rt * FC1_NC + c) * 8 + wave * 2) * 10;
            partials[base + b]      = v0;
            partials[base + 10 + b] = v1;
        }
    }
}

// ================= tail: fc1-reduce + fc2 + fc3 + qnn + RBF cls =================
// 1 block x 1024 threads.
__global__ __launch_bounds__(1024) void tail_k(
    const float* __restrict__ fc1_part, const float* __restrict__ fc1_b,
    const float* __restrict__ fc2_w, const float* __restrict__ fc2_b,
    const float* __restrict__ fc3_w, const float* __restrict__ fc3_b,
    const float* __restrict__ qw1, const float* __restrict__ qw2,
    const float* __restrict__ ts /*(8192,5)*/, const float* __restrict__ kw /*(2,8192)*/,
    const float* __restrict__ kb, float* __restrict__ out /*(2,)*/) {
    __shared__ float s_act[1200];   // [b*120+row]
    __shared__ float s_fc2[840];
    __shared__ float s_h3[10], s_s1[20], s_fs[5];
    __shared__ float red0[16], red1[16];
    int tid = threadIdx.x;

    // fc1 reduce + bias + relu
    for (int i = tid; i < 1200; i += 1024) {
        int b = i % 10, row = i / 10;
        int rt = row >> 3, r = row & 7;
        float s = 0.f;
        const float* p = fc1_part + (((size_t)rt * FC1_NC) * 8 + r) * 10 + b;
        for (int c = 0; c < FC1_NC; ++c) s += p[(size_t)c * 80];
        s_act[b * 120 + row] = fmaxf(s + fc1_b[row], 0.f);
    }
    __syncthreads();

    // fc2 + relu
    for (int p = tid; p < 840; p += 1024) {
        int b = p / 84, j = p % 84;
        float acc = fc2_b[j];
        for (int k = 0; k < 120; ++k) acc += s_act[b * 120 + k] * fc2_w[j * 120 + k];
        s_fc2[b * 84 + j] = fmaxf(acc, 0.f);
    }
    __syncthreads();

    // fc3
    if (tid < 10) {
        float acc = fc3_b[0];
        for (int j = 0; j < 84; ++j) acc += s_fc2[tid * 84 + j] * fc3_w[j];
        s_h3[tid] = acc;
    }
    __syncthreads();
    // qnn layer 1
    if (tid < 20) {
        float acc = 0.f;
        for (int b = 0; b < 10; ++b) acc += qw1[tid * 10 + b] * s_h3[b];
        s_s1[tid] = tanhf(acc);
    }
    __syncthreads();
    // qnn layer 2
    if (tid < 5) {
        float acc = 0.f;
        for (int j = 0; j < 20; ++j) acc += qw2[tid * 20 + j] * s_s1[j];
        s_fs[tid] = tanhf(acc);
    }
    __syncthreads();

    // RBF classifier over 8192 train states
    float f0 = s_fs[0], f1 = s_fs[1], f2 = s_fs[2], f3 = s_fs[3], f4 = s_fs[4];
    float a0 = 0.f, a1 = 0.f;
    #pragma unroll
    for (int k = 0; k < 8; ++k) {
        int n = k * 1024 + tid;
        const float* t = ts + (size_t)n * 5;
        float d0 = f0 - t[0], d1 = f1 - t[1], d2 = f2 - t[2], d3 = f3 - t[3], d4 = f4 - t[4];
        float Kv = expf(-(d0 * d0 + d1 * d1 + d2 * d2 + d3 * d3 + d4 * d4));
        a0 += Kv * kw[n];
        a1 += Kv * kw[8192 + n];
    }
    for (int off = 32; off > 0; off >>= 1) {
        a0 += __shfl_down(a0, off);
        a1 += __shfl_down(a1, off);
    }
    int wave = tid >> 6, lane = tid & 63;
    if (lane == 0) { red0[wave] = a0; red1[wave] = a1; }
    __syncthreads();
    if (tid == 0) { float s = kb[0]; for (int i = 0; i < 16; ++i) s += red0[i]; out[0] = s; }
    if (tid == 1) { float s = kb[1]; for (int i = 0; i < 16; ++i) s += red1[i]; out[1] = s; }
}

extern "C" void kernel_launch(void* const* d_in, const int* in_sizes, int n_in,
                              void* d_out, int out_size, void* d_ws, size_t ws_size,
                              hipStream_t stream) {
    const float* x        = (const float*)d_in[0];
    const float* conv1_w  = (const float*)d_in[1];
    const float* conv1_b  = (const float*)d_in[2];
    const float* conv2_w  = (const float*)d_in[3];
    const float* conv2_b  = (const float*)d_in[4];
    const float* fc1_w    = (const float*)d_in[5];
    const float* fc1_b    = (const float*)d_in[6];
    const float* fc2_w    = (const float*)d_in[7];
    const float* fc2_b    = (const float*)d_in[8];
    const float* fc3_w    = (const float*)d_in[9];
    const float* fc3_b    = (const float*)d_in[10];
    const float* qnn_w1   = (const float*)d_in[11];
    const float* qnn_w2   = (const float*)d_in[12];
    const float* tstates  = (const float*)d_in[13];
    const float* kcls_w   = (const float*)d_in[14];
    const float* kcls_b   = (const float*)d_in[15];

    float* ws = (float*)d_ws;
    float* p1       = ws;                  // 10*6*123*123  = 907740
    float* p2       = p1 + 907740;         // 10*15*61*61   = 558150
    float* fc1_part = p2 + 558150;         // 15*37*80      = 44400

    convpool1_k<<<dim3(10, 62), 256, 0, stream>>>(x, conv1_w, conv1_b, p1);
    convpool2_k<<<dim3(10, 31), 192, 0, stream>>>(p1, conv2_w, conv2_b, p2);
    fc1_partial_k<<<dim3(FC1_RT, FC1_NC), 256, 0, stream>>>(p2, fc1_w, fc1_part);
    tail_k<<<1, 1024, 0, stream>>>(fc1_part, fc1_b, fc2_w, fc2_b, fc3_w, fc3_b,
                                   qnn_w1, qnn_w2, tstates, kcls_w, kcls_b,
                                   (float*)d_out);
}

// Round 4
// 94.416 us; speedup vs baseline: 2.1208x; 1.0211x over previous
//
#include <hip/hip_runtime.h>

// ---------------------------------------------------------------------------
//  x (10,3,250,250)
//  conv1 5x5 s2 p1 + relu -> (10,6,124,124); pool 2x2 s1 -> p1 (10,6,123,123)
//  conv2 3x3 s2 p1 + relu -> (10,15,62,62);  pool 2x2 s1 -> p2 (10,15,61,61)
//  fc1 (120,55815) relu -> (10,120)  [split-K partials, reduced in tail]
//  fc2 (84,120) relu, fc3 (1,84), qnn tanh x2 -> fs (5,)
//  RBF vs train_states (8192,5) -> K -> out (1,2)
// ---------------------------------------------------------------------------

// ===== conv1 + relu + pool fused. grid (10, 62, 2), block 256 =====
// Tile: 2 pool rows (3 conv rows, 9 input rows) x 62-col half (63 conv cols,
// 129 input cols). All divisors compile-time constants.
__global__ __launch_bounds__(256) void convpool1_k(
    const float* __restrict__ x, const float* __restrict__ w,
    const float* __restrict__ bias, float* __restrict__ out /*(10,6,123,123)*/) {
    const int b   = blockIdx.x;
    const int py0 = blockIdx.y * 2;
    const int px0 = blockIdx.z * 62;
    const int n_py = (123 - py0) < 2 ? (123 - py0) : 2;
    const int n_oy = n_py + 1;
    const int iy0 = 2 * py0 - 1;
    const int ix0 = 2 * px0 - 1;

    __shared__ float sx[3][9][132];   // input tile
    __shared__ float so[6][3][64];    // conv outputs

    const int tid = threadIdx.x;

    // ---- stage 3 x 9 x 129 (coalesced, zero-padded) ----
    for (int j = tid; j < 3 * 9 * 129; j += 256) {
        int col = j % 129;            // const divisors -> magic mul
        int r   = (j / 129) % 9;
        int ic  = j / (129 * 9);
        int ix = ix0 + col, iy = iy0 + r;
        float v = 0.f;
        if ((unsigned)ix < 250u && (unsigned)iy < 250u)
            v = x[((size_t)(b * 3 + ic) * 250 + iy) * 250 + ix];
        sx[ic][r][col] = v;
    }
    __syncthreads();

    // ---- conv: each thread one (oyl, oxl) for all 6 oc ----
    for (int p = tid; p < n_oy * 63; p += 256) {
        int oxl = p % 63;
        int oyl = p / 63;
        if (px0 + oxl < 124) {
            float acc[6];
            #pragma unroll
            for (int o = 0; o < 6; ++o) acc[o] = bias[o];
            #pragma unroll
            for (int ic = 0; ic < 3; ++ic) {
                #pragma unroll
                for (int ky = 0; ky < 5; ++ky) {
                    const float* xr = &sx[ic][2 * oyl + ky][2 * oxl];
                    #pragma unroll
                    for (int kx = 0; kx < 5; ++kx) {
                        float xv = xr[kx];
                        #pragma unroll
                        for (int o = 0; o < 6; ++o)
                            acc[o] += w[((o * 3 + ic) * 5 + ky) * 5 + kx] * xv;
                    }
                }
            }
            #pragma unroll
            for (int o = 0; o < 6; ++o) so[o][oyl][oxl] = fmaxf(acc[o], 0.f);
        }
    }
    __syncthreads();

    // ---- pool 2x2 s1 + store: 6 oc x 2 py x 62 px jobs ----
    for (int j = tid; j < 6 * 2 * 62; j += 256) {
        int pxl = j % 62;
        int pyl = (j / 62) & 1;
        int oc  = j / 124;
        int px = px0 + pxl, py = py0 + pyl;
        if (pyl < n_py && px < 123) {
            float v = fmaxf(fmaxf(so[oc][pyl][pxl],     so[oc][pyl][pxl + 1]),
                            fmaxf(so[oc][pyl + 1][pxl], so[oc][pyl + 1][pxl + 1]));
            out[((size_t)(b * 6 + oc) * 123 + py) * 123 + px] = v;
        }
    }
}

// ===== conv2 + relu + pool fused. grid (10, 31, 2), block 128 =====
// Tile: 2 pool rows (3 conv rows, 7 input rows) x 31-col half (32 conv cols,
// 65 input cols).
__global__ __launch_bounds__(128) void convpool2_k(
    const float* __restrict__ in /*(10,6,123,123)*/, const float* __restrict__ w,
    const float* __restrict__ bias, float* __restrict__ out /*(10,15,61,61)*/) {
    const int b   = blockIdx.x;
    const int py0 = blockIdx.y * 2;
    const int px0 = blockIdx.z * 31;
    const int n_py = (61 - py0) < 2 ? (61 - py0) : 2;
    const int n_oy = n_py + 1;
    const int iy0 = 2 * py0 - 1;
    const int ix0 = 2 * px0 - 1;

    __shared__ float sx[6][7][68];
    __shared__ float so[15][3][32];

    const int tid = threadIdx.x;

    // ---- stage 6 x 7 x 65 ----
    for (int j = tid; j < 6 * 7 * 65; j += 128) {
        int col = j % 65;
        int r   = (j / 65) % 7;
        int ic  = j / (65 * 7);
        int ix = ix0 + col, iy = iy0 + r;
        float v = 0.f;
        if ((unsigned)ix < 123u && (unsigned)iy < 123u)
            v = in[((size_t)(b * 6 + ic) * 123 + iy) * 123 + ix];
        sx[ic][r][col] = v;
    }
    __syncthreads();

    // ---- conv: each thread one (oyl, oxl) for all 15 oc ----
    for (int p = tid; p < n_oy * 32; p += 128) {
        int oxl = p % 32;
        int oyl = p / 32;
        if (px0 + oxl < 62) {
            float acc[15];
            #pragma unroll
            for (int o = 0; o < 15; ++o) acc[o] = bias[o];
            #pragma unroll
            for (int ic = 0; ic < 6; ++ic) {
                #pragma unroll
                for (int ky = 0; ky < 3; ++ky) {
                    const float* xr = &sx[ic][2 * oyl + ky][2 * oxl];
                    #pragma unroll
                    for (int kx = 0; kx < 3; ++kx) {
                        float xv = xr[kx];
                        #pragma unroll
                        for (int o = 0; o < 15; ++o)
                            acc[o] += w[((o * 6 + ic) * 3 + ky) * 3 + kx] * xv;
                    }
                }
            }
            #pragma unroll
            for (int o = 0; o < 15; ++o) so[o][oyl][oxl] = fmaxf(acc[o], 0.f);
        }
    }
    __syncthreads();

    // ---- pool: 15 oc x 2 py x 31 px jobs ----
    for (int j = tid; j < 15 * 2 * 31; j += 128) {
        int pxl = j % 31;
        int pyl = (j / 31) & 1;
        int oc  = j / 62;
        int px = px0 + pxl, py = py0 + pyl;
        if (pyl < n_py && px < 61) {
            float v = fmaxf(fmaxf(so[oc][pyl][pxl],     so[oc][pyl][pxl + 1]),
                            fmaxf(so[oc][pyl + 1][pxl], so[oc][pyl + 1][pxl + 1]));
            out[((size_t)(b * 15 + oc) * 61 + py) * 61 + px] = v;
        }
    }
}

// ================= fc1: split-K partials =================
#define FC1_K      55815
#define FC1_CHUNK  1536
#define FC1_NC     37
#define FC1_RT     15

// grid (15, 37), block 256. Wave w owns rows rt*8 + {2w, 2w+1}.
// partials laid out [37][120][10] so the tail reduce is coalesced.
__global__ __launch_bounds__(256) void fc1_partial_k(
    const float* __restrict__ act /*(10,K)*/,
    const float* __restrict__ w   /*(120,K)*/,
    float* __restrict__ partials  /*(37,120,10)*/) {
    int rt  = blockIdx.x;
    int c   = blockIdx.y;
    int tid = threadIdx.x;
    int wave = tid >> 6, lane = tid & 63;
    int k0 = c * FC1_CHUNK;
    int k1 = k0 + FC1_CHUNK; if (k1 > FC1_K) k1 = FC1_K;
    int r0 = rt * 8 + wave * 2;
    const float* w0 = w + (size_t)r0 * FC1_K;
    const float* w1 = w + (size_t)(r0 + 1) * FC1_K;

    float acc0[10], acc1[10];
    #pragma unroll
    for (int b = 0; b < 10; ++b) { acc0[b] = 0.f; acc1[b] = 0.f; }

    for (int k = k0 + lane; k < k1; k += 64) {
        float a[10];
        #pragma unroll
        for (int b = 0; b < 10; ++b) a[b] = act[(size_t)b * FC1_K + k];
        float wv0 = w0[k];
        float wv1 = w1[k];
        #pragma unroll
        for (int b = 0; b < 10; ++b) {
            acc0[b] += wv0 * a[b];
            acc1[b] += wv1 * a[b];
        }
    }
    #pragma unroll
    for (int b = 0; b < 10; ++b) {
        float v0 = acc0[b], v1 = acc1[b];
        for (int off = 32; off > 0; off >>= 1) {
            v0 += __shfl_down(v0, off);
            v1 += __shfl_down(v1, off);
        }
        if (lane == 0) {
            size_t base = ((size_t)c * 120 + r0) * 10;
            partials[base + b]      = v0;
            partials[base + 10 + b] = v1;
        }
    }
}

// ===== tail: fc1-reduce + fc2 + fc3 + qnn + RBF cls. 1 block x 1024 =====
__global__ __launch_bounds__(1024) void tail_k(
    const float* __restrict__ fc1_part /*(37,120,10)*/, const float* __restrict__ fc1_b,
    const float* __restrict__ fc2_w, const float* __restrict__ fc2_b,
    const float* __restrict__ fc3_w, const float* __restrict__ fc3_b,
    const float* __restrict__ qw1, const float* __restrict__ qw2,
    const float* __restrict__ ts /*(8192,5)*/, const float* __restrict__ kw /*(2,8192)*/,
    const float* __restrict__ kb, float* __restrict__ out /*(2,)*/) {
    __shared__ float s_act[1200];   // [b*120+row]
    __shared__ float s_fc2[840];
    __shared__ float s_h3[10], s_s1[20], s_fs[5];
    __shared__ float s_ts[5120];    // 1024 train rows per chunk
    __shared__ float red0[16], red1[16];
    int tid = threadIdx.x;

    // fc1 reduce + bias + relu (coalesced: consecutive tid -> consecutive addr)
    for (int i = tid; i < 1200; i += 1024) {
        int b = i % 10, row = i / 10;
        float s = 0.f;
        #pragma unroll 4
        for (int c = 0; c < FC1_NC; ++c) s += fc1_part[((size_t)c * 120 + row) * 10 + b];
        s_act[b * 120 + row] = fmaxf(s + fc1_b[row], 0.f);
    }
    __syncthreads();

    // fc2 + relu
    for (int p = tid; p < 840; p += 1024) {
        int b = p / 84, j = p % 84;
        float acc = fc2_b[j];
        for (int k = 0; k < 120; ++k) acc += s_act[b * 120 + k] * fc2_w[j * 120 + k];
        s_fc2[b * 84 + j] = fmaxf(acc, 0.f);
    }
    __syncthreads();

    if (tid < 10) {
        float acc = fc3_b[0];
        for (int j = 0; j < 84; ++j) acc += s_fc2[tid * 84 + j] * fc3_w[j];
        s_h3[tid] = acc;
    }
    __syncthreads();
    if (tid < 20) {
        float acc = 0.f;
        for (int b = 0; b < 10; ++b) acc += qw1[tid * 10 + b] * s_h3[b];
        s_s1[tid] = tanhf(acc);
    }
    __syncthreads();
    if (tid < 5) {
        float acc = 0.f;
        for (int j = 0; j < 20; ++j) acc += qw2[tid * 20 + j] * s_s1[j];
        s_fs[tid] = tanhf(acc);
    }
    __syncthreads();

    // RBF classifier over 8192 train states, ts staged via LDS (coalesced)
    float f0 = s_fs[0], f1 = s_fs[1], f2 = s_fs[2], f3 = s_fs[3], f4 = s_fs[4];
    float a0 = 0.f, a1 = 0.f;
    for (int ch = 0; ch < 8; ++ch) {
        for (int j = tid; j < 5120; j += 1024) s_ts[j] = ts[ch * 5120 + j];
        __syncthreads();
        int n = ch * 1024 + tid;
        const float* t = &s_ts[tid * 5];
        float d0 = f0 - t[0], d1 = f1 - t[1], d2 = f2 - t[2], d3 = f3 - t[3], d4 = f4 - t[4];
        float Kv = expf(-(d0 * d0 + d1 * d1 + d2 * d2 + d3 * d3 + d4 * d4));
        a0 += Kv * kw[n];
        a1 += Kv * kw[8192 + n];
        __syncthreads();
    }
    for (int off = 32; off > 0; off >>= 1) {
        a0 += __shfl_down(a0, off);
        a1 += __shfl_down(a1, off);
    }
    int wave = tid >> 6, lane = tid & 63;
    if (lane == 0) { red0[wave] = a0; red1[wave] = a1; }
    __syncthreads();
    if (tid == 0) { float s = kb[0]; for (int i = 0; i < 16; ++i) s += red0[i]; out[0] = s; }
    if (tid == 1) { float s = kb[1]; for (int i = 0; i < 16; ++i) s += red1[i]; out[1] = s; }
}

extern "C" void kernel_launch(void* const* d_in, const int* in_sizes, int n_in,
                              void* d_out, int out_size, void* d_ws, size_t ws_size,
                              hipStream_t stream) {
    const float* x        = (const float*)d_in[0];
    const float* conv1_w  = (const float*)d_in[1];
    const float* conv1_b  = (const float*)d_in[2];
    const float* conv2_w  = (const float*)d_in[3];
    const float* conv2_b  = (const float*)d_in[4];
    const float* fc1_w    = (const float*)d_in[5];
    const float* fc1_b    = (const float*)d_in[6];
    const float* fc2_w    = (const float*)d_in[7];
    const float* fc2_b    = (const float*)d_in[8];
    const float* fc3_w    = (const float*)d_in[9];
    const float* fc3_b    = (const float*)d_in[10];
    const float* qnn_w1   = (const float*)d_in[11];
    const float* qnn_w2   = (const float*)d_in[12];
    const float* tstates  = (const float*)d_in[13];
    const float* kcls_w   = (const float*)d_in[14];
    const float* kcls_b   = (const float*)d_in[15];

    float* ws = (float*)d_ws;
    float* p1       = ws;                  // 10*6*123*123  = 907740
    float* p2       = p1 + 907740;         // 10*15*61*61   = 558150
    float* fc1_part = p2 + 558150;         // 37*120*10     = 44400

    convpool1_k<<<dim3(10, 62, 2), 256, 0, stream>>>(x, conv1_w, conv1_b, p1);
    convpool2_k<<<dim3(10, 31, 2), 128, 0, stream>>>(p1, conv2_w, conv2_b, p2);
    fc1_partial_k<<<dim3(FC1_RT, FC1_NC), 256, 0, stream>>>(p2, fc1_w, fc1_part);
    tail_k<<<1, 1024, 0, stream>>>(fc1_part, fc1_b, fc2_w, fc2_b, fc3_w, fc3_b,
                                   qnn_w1, qnn_w2, tstates, kcls_w, kcls_b,
                                   (float*)d_out);
}